// Round 1
// baseline (47.435 us; speedup 1.0000x reference)
//
#include <hip/hip_runtime.h>
#include <hip/hip_bf16.h>

// Fused rule-based LM: fills logits [L,16], attn [L,L], h [L,64] (all fp32).
// One block per row i. All predicates (cond, prev_action) are block-uniform.
// Memory-bound: ~258.5 MB of stores dominate -> target HBM write roofline.

#define VOCAB 16
#define DIM 64
#define NEGV -1e9f

__global__ __launch_bounds__(256) void rulelm_fused(
    const int* __restrict__ ids,
    const float* __restrict__ emb,
    float* __restrict__ logits,
    float* __restrict__ attn,
    float* __restrict__ h,
    int L)
{
    const int i   = blockIdx.x;
    const int tid = threadIdx.x;

    const int id  = ids[i];
    const int idp = (i > 0) ? ids[i - 1] : -1;

    const bool prev_action = (i > 0) && (idp >= 7 && idp <= 9);
    const bool is_pref     = (id == 10) || (id == 11);
    const bool cond        = is_pref && prev_action;

    // ---- attention row: constant fill + single 0.8 fixup ----
    const float each = 0.2f / (float)(L - 1);
    const float base = cond ? each : (1.0f / (float)L);
    float4 fill = make_float4(base, base, base, base);

    float4* arow = (float4*)(attn + (size_t)i * (size_t)L);
    const int nvec = L >> 2;  // float4s per row

    if (cond) {
        const int special = i - 1;  // column holding 0.8
        for (int k = tid; k < nvec; k += 256) {
            float4 w = fill;
            const int c0 = k << 2;
            if (special >= c0 && special < c0 + 4) {
                ((float*)&w)[special - c0] = 0.8f;
            }
            arow[k] = w;
        }
    } else {
        for (int k = tid; k < nvec; k += 256) {
            arow[k] = fill;
        }
    }

    // ---- logits row (16 values) ----
    if (tid < VOCAB) {
        float val;
        const bool tok_pref = (tid == 10) || (tid == 11);
        if (i == 0) {
            val = NEGV;
        } else if (prev_action) {
            val = tok_pref ? 5.0f : NEGV;
        } else {
            val = tok_pref ? -5.0f : ((tid <= 2) ? NEGV : 1.0f);
        }
        logits[(size_t)i * VOCAB + tid] = val;
    }

    // ---- hidden row: 64 floats = 16 float4 from emb[id] ----
    if (tid >= 64 && tid < 80) {
        const int q = tid - 64;
        ((float4*)(h + (size_t)i * DIM))[q] =
            ((const float4*)(emb + (size_t)id * DIM))[q];
    }
}

extern "C" void kernel_launch(void* const* d_in, const int* in_sizes, int n_in,
                              void* d_out, int out_size, void* d_ws, size_t ws_size,
                              hipStream_t stream)
{
    const int*   ids = (const int*)d_in[0];
    const float* emb = (const float*)d_in[1];
    const int L = in_sizes[0];  // 8192

    float* out    = (float*)d_out;
    float* logits = out;                                  // L*16
    float* attn   = out + (size_t)L * VOCAB;              // L*L
    float* h      = attn + (size_t)L * (size_t)L;         // L*64

    rulelm_fused<<<L, 256, 0, stream>>>(ids, emb, logits, attn, h, L);
}